// Round 4
// baseline (365.838 us; speedup 1.0000x reference)
//
#include <hip/hip_runtime.h>
#include <hip/hip_bf16.h>

// GaussianPolicy: SNN-LIF frontend + 2-branch MLP heads.
// B=4096, IN=512, H=2048, A=32. fp32 in/out; fp16 MFMA compute internally.
// Trunk GEMMs use a 4-slot LDS ring + counted vmcnt(8) (never drain to 0 in
// the main loop) so global_load_lds prefetches stay in flight across barriers.

typedef _Float16 f16;
using f32x4 = __attribute__((ext_vector_type(4))) float;
using f16x8 = __attribute__((ext_vector_type(8))) f16;   // 8 fp16 = 4 VGPRs

#define MFMA16(a, b, c) __builtin_amdgcn_mfma_f32_16x16x32_f16((a), (b), (c), 0, 0, 0)

__device__ __forceinline__ void gload16(const void* g, void* l) {
  // async global->LDS, 16B/lane; LDS dest must be wave-uniform base + lane*16
  __builtin_amdgcn_global_load_lds(
      (const __attribute__((address_space(1))) unsigned int*)g,
      (__attribute__((address_space(3))) unsigned int*)l, 16, 0, 0);
}

// ---------------------------------------------------------------------------
// fp32 -> fp16 convert, 8 elems/thread
// ---------------------------------------------------------------------------
__global__ __launch_bounds__(256) void cvt_kernel(
    const float* __restrict__ src, f16* __restrict__ dst, int n8)
{
  int i = blockIdx.x * 256 + threadIdx.x;
  if (i >= n8) return;
  const float4* s4 = (const float4*)src;
  float4 a = s4[(size_t)i * 2], b = s4[(size_t)i * 2 + 1];
  f16x8 d;
  d[0] = (f16)a.x; d[1] = (f16)a.y; d[2] = (f16)a.z; d[3] = (f16)a.w;
  d[4] = (f16)b.x; d[5] = (f16)b.y; d[6] = (f16)b.z; d[7] = (f16)b.w;
  *(f16x8*)(dst + (size_t)i * 8) = d;
}

// two equal-size tensors in one dispatch (saves a launch)
__global__ __launch_bounds__(256) void cvt2_kernel(
    const float* __restrict__ s0, const float* __restrict__ s1,
    f16* __restrict__ d0, f16* __restrict__ d1, int n8each)
{
  int i = blockIdx.x * 256 + threadIdx.x;
  const float* src = (i < n8each) ? s0 : s1;
  f16* dst = (i < n8each) ? d0 : d1;
  int k = (i < n8each) ? i : i - n8each;
  if (k >= n8each) return;
  const float4* s4 = (const float4*)src;
  float4 a = s4[(size_t)k * 2], b = s4[(size_t)k * 2 + 1];
  f16x8 d;
  d[0] = (f16)a.x; d[1] = (f16)a.y; d[2] = (f16)a.z; d[3] = (f16)a.w;
  d[4] = (f16)b.x; d[5] = (f16)b.y; d[6] = (f16)b.z; d[7] = (f16)b.w;
  *(f16x8*)(dst + (size_t)k * 8) = d;
}

// ---------------------------------------------------------------------------
// LIF kernel: fc[b,s,h] = state_s @ W_lif^T (fp16), 15-step LIF, x = mean.
// Tile 64(M) x 128(N), 4 waves (2x2), wave 32x64; 5 slice accumulators.
// (unchanged from round 3 — proven)
// ---------------------------------------------------------------------------
__global__ __launch_bounds__(256) void lif_kernel(
    const f16* __restrict__ S,    // [4096, 5, 512] fp16
    const f16* __restrict__ W,    // [2048, 512] fp16
    const float* __restrict__ bl, // [2048] fp32
    f16* __restrict__ X)          // [4096, 2048] fp16
{
  const int K = 512, N = 2048;
  __shared__ alignas(16) f16 As[2][5][64 * 32];
  __shared__ alignas(16) f16 Bs[2][128 * 32];

  const int tid = threadIdx.x, wid = tid >> 6, lane = tid & 63;
  const int nwg = 1024, q = nwg / 8;
  const int wg = (blockIdx.x % 8) * q + blockIdx.x / 8;
  const int bm = wg % 64, bn = wg / 64;          // nbm=64, nbn=16
  const int b0 = bm * 64, h0 = bn * 128;
  const int wr = (wid >> 1) * 32, wc = (wid & 1) * 64;
  const int srow = tid >> 2, skol = (tid & 3) * 8;
  const int kb = (lane >> 4) * 8, fr = lane & 15, fq = lane >> 4;

  f32x4 acc[5][2][4] = {};

  auto STAGE = [&](int p, int k0) {
#pragma unroll
    for (int s = 0; s < 5; ++s)
      gload16(S + ((size_t)(b0 + srow) * 5 + s) * K + k0 + skol, &As[p][s][tid * 8]);
#pragma unroll
    for (int r = 0; r < 2; ++r)
      gload16(W + (size_t)(h0 + r * 64 + srow) * K + k0 + skol, &Bs[p][r * 2048 + tid * 8]);
  };

  STAGE(0, 0);
  __syncthreads();
  int cur = 0;
  for (int kt = 0; kt < 16; ++kt) {
    if (kt + 1 < 16) STAGE(cur ^ 1, (kt + 1) * 32);
    f16x8 bf[4];
#pragma unroll
    for (int n = 0; n < 4; ++n)
      bf[n] = *(const f16x8*)&Bs[cur][(wc + n * 16 + fr) * 32 + kb];
#pragma unroll
    for (int s = 0; s < 5; ++s) {
      f16x8 af[2];
#pragma unroll
      for (int m = 0; m < 2; ++m)
        af[m] = *(const f16x8*)&As[cur][s][(wr + m * 16 + fr) * 32 + kb];
#pragma unroll
      for (int m = 0; m < 2; ++m)
#pragma unroll
        for (int n = 0; n < 4; ++n)
          acc[s][m][n] = MFMA16(af[m], bf[n], acc[s][m][n]);
    }
    __syncthreads();
    cur ^= 1;
  }

#pragma unroll
  for (int m = 0; m < 2; ++m) {
#pragma unroll
    for (int n = 0; n < 4; ++n) {
      const int col = h0 + wc + n * 16 + fr;
      const float bv = bl[col];
#pragma unroll
      for (int r = 0; r < 4; ++r) {
        const int row = b0 + wr + m * 16 + fq * 4 + r;
        float mem = 0.f, spk = 0.f, cnt = 0.f;
#pragma unroll
        for (int s = 0; s < 5; ++s) {
          const float fc = acc[s][m][n][r] + bv;
#pragma unroll
          for (int j = 0; j < 3; ++j) {
            mem = mem * 0.2f * (1.f - spk) + fc;   // DECAY=0.2
            spk = (mem > 0.2f) ? 1.f : 0.f;        // THRESH=0.2
            cnt += spk;
          }
        }
        X[(size_t)row * N + col] = (f16)(cnt / 15.0f);
      }
    }
  }
}

// ---------------------------------------------------------------------------
// Trunk GEMM: C = relu(A @ W^T + bias), fp16 in/out, fp32 bias/accum.
// 128x128 tile, BK=32, 4 waves. 4-slot LDS ring, stage tile j+3 during tile j,
// counted s_waitcnt vmcnt(8) at the per-iter barrier (never drain mid-loop).
// Two column-halves may use different A/W/bias/C (layer fusion).
// ---------------------------------------------------------------------------
__global__ __launch_bounds__(256) void trunk_kernel(
    const f16* __restrict__ A0, const f16* __restrict__ A1, int lda,
    const f16* __restrict__ W0, const f16* __restrict__ W1,
    const float* __restrict__ bb0, const float* __restrict__ bb1,
    f16* __restrict__ C0, f16* __restrict__ C1, int ldc,
    int nbm, int nbn_total, int nbn_half, int K)
{
  __shared__ alignas(16) f16 As[4][128 * 32];   // 4-slot ring, 8KB/slot
  __shared__ alignas(16) f16 Bs[4][128 * 32];

  const int tid = threadIdx.x, wid = tid >> 6, lane = tid & 63;
  const int nwg = nbm * nbn_total, q = nwg / 8;
  const int wg = (blockIdx.x % 8) * q + blockIdx.x / 8;
  const int bmi = wg % nbm, t = wg / nbm;
  const int half = (t >= nbn_half);
  const f16* A = half ? A1 : A0;
  const f16* W = half ? W1 : W0;
  const float* bias = half ? bb1 : bb0;
  f16* C = half ? C1 : C0;
  const int bm0 = bmi * 128;
  const int bn0 = (half ? t - nbn_half : t) * 128;

  const int wr = (wid >> 1) * 64, wc = (wid & 1) * 64;
  const int srow = tid >> 2, skol = (tid & 3) * 8;
  const int kb = (lane >> 4) * 8, fr = lane & 15, fq = lane >> 4;

  f32x4 acc[4][4] = {};

  auto STAGE = [&](int slot, int k0) {
    gload16(A + (size_t)(bm0 + srow) * lda + k0 + skol,      &As[slot][tid * 8]);
    gload16(A + (size_t)(bm0 + 64 + srow) * lda + k0 + skol, &As[slot][2048 + tid * 8]);
    gload16(W + (size_t)(bn0 + srow) * K + k0 + skol,        &Bs[slot][tid * 8]);
    gload16(W + (size_t)(bn0 + 64 + srow) * K + k0 + skol,   &Bs[slot][2048 + tid * 8]);
  };

  const int NT = K / 32;   // 64 here; requires NT >= 4
  STAGE(0, 0);
  STAGE(1, 32);
  STAGE(2, 64);
  // tile 0 ready; tiles 1,2 (8 loads) stay in flight
  __builtin_amdgcn_sched_barrier(0);
  asm volatile("s_waitcnt vmcnt(8)" ::: "memory");
  __builtin_amdgcn_s_barrier();
  __builtin_amdgcn_sched_barrier(0);

  for (int j = 0; j < NT; ++j) {
    const int slot = j & 3;
    if (j + 3 < NT) STAGE((j + 3) & 3, (j + 3) * 32);   // slot (j+3)&3 = (j-1)&3: reads done

    f16x8 af[4], bf[4];
#pragma unroll
    for (int m = 0; m < 4; ++m)
      af[m] = *(const f16x8*)&As[slot][(wr + m * 16 + fr) * 32 + kb];
#pragma unroll
    for (int n = 0; n < 4; ++n)
      bf[n] = *(const f16x8*)&Bs[slot][(wc + n * 16 + fr) * 32 + kb];
#pragma unroll
    for (int m = 0; m < 4; ++m)
#pragma unroll
      for (int n = 0; n < 4; ++n)
        acc[m][n] = MFMA16(af[m], bf[n], acc[m][n]);

    if (j + 1 < NT) {
      // in-flight beyond tile j+1: tiles up to min(j+3, NT-1)
      const int ahead = (j + 3 < NT) ? 2 : (NT - 2 - j);  // 2, 1, or 0
      __builtin_amdgcn_sched_barrier(0);
      if (ahead == 2)      asm volatile("s_waitcnt vmcnt(8)" ::: "memory");
      else if (ahead == 1) asm volatile("s_waitcnt vmcnt(4)" ::: "memory");
      else                 asm volatile("s_waitcnt vmcnt(0)" ::: "memory");
      __builtin_amdgcn_s_barrier();
      __builtin_amdgcn_sched_barrier(0);
    }
  }

#pragma unroll
  for (int n = 0; n < 4; ++n) {
    const int col = bn0 + wc + n * 16 + fr;
    const float bv = bias[col];
#pragma unroll
    for (int m = 0; m < 4; ++m) {
      const int row0 = bm0 + wr + m * 16 + fq * 4;
#pragma unroll
      for (int r = 0; r < 4; ++r) {
        float v = fmaxf(acc[m][n][r] + bv, 0.f);
        C[(size_t)(row0 + r) * ldc + col] = (f16)v;
      }
    }
  }
}

// ---------------------------------------------------------------------------
// Heads: mean = h12@Wm^T + bm ; log_std = clip(h22@Wls^T + bls, -20, 2). fp32 out.
// ---------------------------------------------------------------------------
__global__ __launch_bounds__(256) void head_kernel(
    const f16* __restrict__ H1, const f16* __restrict__ H2,
    const f16* __restrict__ Wm, const float* __restrict__ bm,
    const f16* __restrict__ Wls, const float* __restrict__ bls,
    float* __restrict__ OUT, int M, int K)
{
  const int tid = threadIdx.x, wid = tid >> 6, lane = tid & 63;
  const int m0 = blockIdx.x * 64 + wid * 16;
  const int kb = (lane >> 4) * 8, fr = lane & 15, fq = lane >> 4;

  f32x4 a1[2] = {}, a2[2] = {};
  for (int k0 = 0; k0 < K; k0 += 32) {
    f16x8 f1 = *(const f16x8*)&H1[(size_t)(m0 + fr) * K + k0 + kb];
    f16x8 f2 = *(const f16x8*)&H2[(size_t)(m0 + fr) * K + k0 + kb];
#pragma unroll
    for (int n = 0; n < 2; ++n) {
      f16x8 wm = *(const f16x8*)&Wm[(size_t)(n * 16 + fr) * K + k0 + kb];
      f16x8 wl = *(const f16x8*)&Wls[(size_t)(n * 16 + fr) * K + k0 + kb];
      a1[n] = MFMA16(f1, wm, a1[n]);
      a2[n] = MFMA16(f2, wl, a2[n]);
    }
  }

#pragma unroll
  for (int n = 0; n < 2; ++n) {
    const int col = n * 16 + fr;
    const float bvm = bm[col];
    const float bvl = bls[col];
#pragma unroll
    for (int r = 0; r < 4; ++r) {
      const int row = m0 + fq * 4 + r;
      OUT[(size_t)row * 32 + col] = a1[n][r] + bvm;
      float lv = a2[n][r] + bvl;
      OUT[(size_t)M * 32 + (size_t)row * 32 + col] = fminf(fmaxf(lv, -20.f), 2.f);
    }
  }
}

// ---------------------------------------------------------------------------
extern "C" void kernel_launch(void* const* d_in, const int* in_sizes, int n_in,
                              void* d_out, int out_size, void* d_ws, size_t ws_size,
                              hipStream_t stream) {
  const float* state = (const float*)d_in[0];
  const float* W_lif = (const float*)d_in[1];
  const float* b_lif = (const float*)d_in[2];
  const float* W11   = (const float*)d_in[3];
  const float* b11   = (const float*)d_in[4];
  const float* W12   = (const float*)d_in[5];
  const float* b12   = (const float*)d_in[6];
  const float* W21   = (const float*)d_in[7];
  const float* b21   = (const float*)d_in[8];
  const float* W22   = (const float*)d_in[9];
  const float* b22   = (const float*)d_in[10];
  const float* Wm    = (const float*)d_in[11];
  const float* bm    = (const float*)d_in[12];
  const float* Wls   = (const float*)d_in[13];
  const float* bls   = (const float*)d_in[14];
  float* out = (float*)d_out;

  const int B = 4096, IN = 512, H = 2048;
  char* ws = (char*)d_ws;
  // layout (bytes), peak 80.0 MB (proven ws >= 84.2 MB):
  //   0        x [16.8M]        -> h12 (trunk2 out; x dead after trunk1)
  //   16777216 h1 [16.8M]       (trunk1 out, trunk2 in)
  //   33554432 h2 [16.8M]       (trunk1 out, trunk2 in)
  //   50331648 s16 [21M, lif]   -> w11h+w21h (trunk1 in) -> h22 (trunk2 out)
  //   67108864 w12h [8.4M]      (over wl16 tail; wl16 dead after lif) -> wmh/wlsh
  //   75497472 w22h [8.4M]      ends 83886080
  f16* x    = (f16*)(ws);
  f16* h1   = (f16*)(ws + 16777216);
  f16* h2   = (f16*)(ws + 33554432);
  f16* s16  = (f16*)(ws + 50331648);
  f16* wl16 = (f16*)(ws + 71303168);
  f16* w11h = (f16*)(ws + 50331648);
  f16* w21h = (f16*)(ws + 58720256);
  f16* h22  = (f16*)(ws + 50331648);
  f16* w12h = (f16*)(ws + 67108864);
  f16* w22h = (f16*)(ws + 75497472);
  f16* wmh  = (f16*)(ws + 67108864);
  f16* wlsh = (f16*)(ws + 67239936);
  f16* h12  = x;

  // 1) converts for LIF
  cvt_kernel<<<(B * 5 * IN / 8) / 256, 256, 0, stream>>>(state, s16, B * 5 * IN / 8);
  cvt_kernel<<<(H * IN / 8) / 256, 256, 0, stream>>>(W_lif, wl16, H * IN / 8);

  // 2) fused fc-GEMM + LIF -> x
  lif_kernel<<<1024, 256, 0, stream>>>(s16, wl16, b_lif, x);

  // 3) layer-1: cvt W11+W21 (over s16), fused GEMM -> h1, h2
  cvt2_kernel<<<2 * (H * H / 8) / 256, 256, 0, stream>>>(W11, W21, w11h, w21h, H * H / 8);
  trunk_kernel<<<1024, 256, 0, stream>>>(x, x, H, w11h, w21h, b11, b21,
                                         h1, h2, H, 32, 32, 16, H);

  // 4) layer-2: cvt W12+W22, fused GEMM -> h12 (over x), h22 (over w11h/w21h)
  cvt2_kernel<<<2 * (H * H / 8) / 256, 256, 0, stream>>>(W12, W22, w12h, w22h, H * H / 8);
  trunk_kernel<<<1024, 256, 0, stream>>>(h1, h2, H, w12h, w22h, b12, b22,
                                         h12, h22, H, 32, 32, 16, H);

  // 5) heads -> d_out = [mean | log_std] fp32
  cvt2_kernel<<<2 * (32 * H / 8) / 256, 256, 0, stream>>>(Wm, Wls, wmh, wlsh, 32 * H / 8);
  head_kernel<<<B / 64, 256, 0, stream>>>(h12, h22, wmh, bm, wlsh, bls, out, B, H);
}

// Round 5
// 295.785 us; speedup vs baseline: 1.2368x; 1.2368x over previous
//
#include <hip/hip_runtime.h>
#include <hip/hip_bf16.h>

// GaussianPolicy: SNN-LIF frontend + 2-branch MLP heads.
// B=4096, IN=512, H=2048, A=32. fp32 in/out; fp16 MFMA compute internally.
// Trunk GEMMs: 256x256 tile, BK=64, 8 waves, XOR-swizzled LDS (T2),
// register-resident MFMA clusters + counted vmcnt(8) pipeline (T3/T4), T5.

typedef _Float16 f16;
using f32x4 = __attribute__((ext_vector_type(4))) float;
using f16x8 = __attribute__((ext_vector_type(8))) f16;   // 8 fp16 = 4 VGPRs

#define MFMA16(a, b, c) __builtin_amdgcn_mfma_f32_16x16x32_f16((a), (b), (c), 0, 0, 0)
#define VMW8()  asm volatile("s_waitcnt vmcnt(8)" ::: "memory")
#define VMW0()  asm volatile("s_waitcnt vmcnt(0)" ::: "memory")
#define LGKM0() asm volatile("s_waitcnt lgkmcnt(0)" ::: "memory")
#define BARRIER() __builtin_amdgcn_s_barrier()
#define SCHED0() __builtin_amdgcn_sched_barrier(0)

__device__ __forceinline__ void gload16(const void* g, void* l) {
  // async global->LDS, 16B/lane; LDS dest must be wave-uniform base + lane*16
  __builtin_amdgcn_global_load_lds(
      (const __attribute__((address_space(1))) unsigned int*)g,
      (__attribute__((address_space(3))) unsigned int*)l, 16, 0, 0);
}

// ---------------------------------------------------------------------------
// fp32 -> fp16 convert, 8 elems/thread
// ---------------------------------------------------------------------------
__global__ __launch_bounds__(256) void cvt_kernel(
    const float* __restrict__ src, f16* __restrict__ dst, int n8)
{
  int i = blockIdx.x * 256 + threadIdx.x;
  if (i >= n8) return;
  const float4* s4 = (const float4*)src;
  float4 a = s4[(size_t)i * 2], b = s4[(size_t)i * 2 + 1];
  f16x8 d;
  d[0] = (f16)a.x; d[1] = (f16)a.y; d[2] = (f16)a.z; d[3] = (f16)a.w;
  d[4] = (f16)b.x; d[5] = (f16)b.y; d[6] = (f16)b.z; d[7] = (f16)b.w;
  *(f16x8*)(dst + (size_t)i * 8) = d;
}

// two equal-size tensors in one dispatch (saves a launch)
__global__ __launch_bounds__(256) void cvt2_kernel(
    const float* __restrict__ s0, const float* __restrict__ s1,
    f16* __restrict__ d0, f16* __restrict__ d1, int n8each)
{
  int i = blockIdx.x * 256 + threadIdx.x;
  const float* src = (i < n8each) ? s0 : s1;
  f16* dst = (i < n8each) ? d0 : d1;
  int k = (i < n8each) ? i : i - n8each;
  if (k >= n8each) return;
  const float4* s4 = (const float4*)src;
  float4 a = s4[(size_t)k * 2], b = s4[(size_t)k * 2 + 1];
  f16x8 d;
  d[0] = (f16)a.x; d[1] = (f16)a.y; d[2] = (f16)a.z; d[3] = (f16)a.w;
  d[4] = (f16)b.x; d[5] = (f16)b.y; d[6] = (f16)b.z; d[7] = (f16)b.w;
  *(f16x8*)(dst + (size_t)k * 8) = d;
}

// ---------------------------------------------------------------------------
// LIF kernel: fc[b,s,h] = state_s @ W_lif^T (fp16), 15-step LIF, x = mean.
// Tile 64(M) x 128(N), 4 waves (2x2), wave 32x64; 5 slice accumulators.
// (unchanged — proven)
// ---------------------------------------------------------------------------
__global__ __launch_bounds__(256) void lif_kernel(
    const f16* __restrict__ S,    // [4096, 5, 512] fp16
    const f16* __restrict__ W,    // [2048, 512] fp16
    const float* __restrict__ bl, // [2048] fp32
    f16* __restrict__ X)          // [4096, 2048] fp16
{
  const int K = 512, N = 2048;
  __shared__ alignas(16) f16 As[2][5][64 * 32];
  __shared__ alignas(16) f16 Bs[2][128 * 32];

  const int tid = threadIdx.x, wid = tid >> 6, lane = tid & 63;
  const int nwg = 1024, q = nwg / 8;
  const int wg = (blockIdx.x % 8) * q + blockIdx.x / 8;
  const int bm = wg % 64, bn = wg / 64;          // nbm=64, nbn=16
  const int b0 = bm * 64, h0 = bn * 128;
  const int wr = (wid >> 1) * 32, wc = (wid & 1) * 64;
  const int srow = tid >> 2, skol = (tid & 3) * 8;
  const int kb = (lane >> 4) * 8, fr = lane & 15, fq = lane >> 4;

  f32x4 acc[5][2][4] = {};

  auto STAGE = [&](int p, int k0) {
#pragma unroll
    for (int s = 0; s < 5; ++s)
      gload16(S + ((size_t)(b0 + srow) * 5 + s) * K + k0 + skol, &As[p][s][tid * 8]);
#pragma unroll
    for (int r = 0; r < 2; ++r)
      gload16(W + (size_t)(h0 + r * 64 + srow) * K + k0 + skol, &Bs[p][r * 2048 + tid * 8]);
  };

  STAGE(0, 0);
  __syncthreads();
  int cur = 0;
  for (int kt = 0; kt < 16; ++kt) {
    if (kt + 1 < 16) STAGE(cur ^ 1, (kt + 1) * 32);
    f16x8 bf[4];
#pragma unroll
    for (int n = 0; n < 4; ++n)
      bf[n] = *(const f16x8*)&Bs[cur][(wc + n * 16 + fr) * 32 + kb];
#pragma unroll
    for (int s = 0; s < 5; ++s) {
      f16x8 af[2];
#pragma unroll
      for (int m = 0; m < 2; ++m)
        af[m] = *(const f16x8*)&As[cur][s][(wr + m * 16 + fr) * 32 + kb];
#pragma unroll
      for (int m = 0; m < 2; ++m)
#pragma unroll
        for (int n = 0; n < 4; ++n)
          acc[s][m][n] = MFMA16(af[m], bf[n], acc[s][m][n]);
    }
    __syncthreads();
    cur ^= 1;
  }

#pragma unroll
  for (int m = 0; m < 2; ++m) {
#pragma unroll
    for (int n = 0; n < 4; ++n) {
      const int col = h0 + wc + n * 16 + fr;
      const float bv = bl[col];
#pragma unroll
      for (int r = 0; r < 4; ++r) {
        const int row = b0 + wr + m * 16 + fq * 4 + r;
        float mem = 0.f, spk = 0.f, cnt = 0.f;
#pragma unroll
        for (int s = 0; s < 5; ++s) {
          const float fc = acc[s][m][n][r] + bv;
#pragma unroll
          for (int j = 0; j < 3; ++j) {
            mem = mem * 0.2f * (1.f - spk) + fc;   // DECAY=0.2
            spk = (mem > 0.2f) ? 1.f : 0.f;        // THRESH=0.2
            cnt += spk;
          }
        }
        X[(size_t)row * N + col] = (f16)(cnt / 15.0f);
      }
    }
  }
}

// ---------------------------------------------------------------------------
// Trunk GEMM: C = relu(A @ W^T + bias), fp16 in/out, fp32 bias/accum.
// 256x256 tile, BK=64, 8 waves (2Mx4N), wave output 128x64 = 8x4 frags.
// LDS: A,B each 2 slots [256][64] f16, XOR-swizzled (c ^= (row&7)<<4) via
// pre-swizzled global source + swizzled ds_read (linear gload_lds dest).
// Per K-tile: [bar] ds_read all frags (quadrant-pipelined with reg-only MFMA)
// -> lgkm0 [bar] -> STAGE tile kt+2 into this slot -> vmcnt(8) [bar].
// Loads for tile kt+2 stay in flight across barriers (never drain mid-loop).
// Two column-halves may use different A/W/bias/C (layer fusion).
// ---------------------------------------------------------------------------
__global__ __launch_bounds__(512, 2) void trunk256_kernel(
    const f16* __restrict__ A0, const f16* __restrict__ A1, int lda,
    const f16* __restrict__ W0, const f16* __restrict__ W1,
    const float* __restrict__ bb0, const float* __restrict__ bb1,
    f16* __restrict__ C0, f16* __restrict__ C1, int ldc,
    int nbm, int nbn_half, int K)
{
  __shared__ alignas(16) f16 lds[4][256 * 64];   // [0,1]=A slots, [2,3]=B slots

  const int tid = threadIdx.x, wid = tid >> 6, lane = tid & 63;
  const int nwg = nbm * nbn_half * 2, q8 = nwg / 8;
  const int wg = ((int)blockIdx.x % 8) * q8 + (int)blockIdx.x / 8;
  const int bmi = wg % nbm, t = wg / nbm;
  const int half = (t >= nbn_half);
  const f16* Ap = half ? A1 : A0;
  const f16* Wp = half ? W1 : W0;
  const float* bias = half ? bb1 : bb0;
  f16* C = half ? C1 : C0;
  const int bm0 = bmi * 256;
  const int bn0 = (half ? t - nbn_half : t) * 256;

  const int wr0 = (wid >> 2) * 128, wc0 = (wid & 3) * 64;
  const int fr = lane & 15, fq = lane >> 4;
  const int sr = tid >> 3, scb = (tid & 7) * 16;   // staging: row-in-64, col byte

  f32x4 acc[8][4] = {};
  const int NT = K / 64;

  // stage one K-tile (A: 4 gloads, B: 4 gloads). Linear LDS dest; source col
  // pre-swizzled so that swizzled ds_read returns logical data (involution).
  auto STAGE = [&](int slot, int kt) {
    const int k0 = kt * 64;
#pragma unroll
    for (int l = 0; l < 4; ++l) {
      const int row = l * 64 + sr;
      const int c2 = scb ^ ((row & 7) << 4);       // source col in bytes
      gload16(Ap + (size_t)(bm0 + row) * lda + k0 + (c2 >> 1),
              &lds[slot][l * 4096 + tid * 8]);
    }
#pragma unroll
    for (int l = 0; l < 4; ++l) {
      const int row = l * 64 + sr;
      const int c2 = scb ^ ((row & 7) << 4);
      gload16(Wp + (size_t)(bn0 + row) * K + k0 + (c2 >> 1),
              &lds[2 + slot][l * 4096 + tid * 8]);
    }
  };

  // swizzled fragment reads (logical row, k-step ks)
  auto LDA_ = [&](int slot, int mf, int ks) -> f16x8 {
    const int row = wr0 + mf * 16 + fr;
    const int c = (ks * 64 + fq * 16) ^ ((row & 7) << 4);
    return *(const f16x8*)&lds[slot][row * 64 + (c >> 1)];
  };
  auto LDB_ = [&](int slot, int nf, int ks) -> f16x8 {
    const int row = wc0 + nf * 16 + fr;
    const int c = (ks * 64 + fq * 16) ^ ((row & 7) << 4);
    return *(const f16x8*)&lds[2 + slot][row * 64 + (c >> 1)];
  };

  STAGE(0, 0);
  STAGE(1, 1);
  VMW8();          // tile 0 landed; tile 1's 8 loads stay in flight
  BARRIER();
  SCHED0();

  for (int kt = 0; kt < NT; ++kt) {
    const int slot = kt & 1;

    f16x8 b[4][2];
#pragma unroll
    for (int nf = 0; nf < 4; ++nf) {
      b[nf][0] = LDB_(slot, nf, 0);
      b[nf][1] = LDB_(slot, nf, 1);
    }
    f16x8 a0[2][2], a1[2][2];
#pragma unroll
    for (int i = 0; i < 2; ++i) {
      a0[i][0] = LDA_(slot, i, 0);
      a0[i][1] = LDA_(slot, i, 1);
    }

    auto QUAD = [&](int mbase, f16x8 (&a)[2][2]) {
      __builtin_amdgcn_s_setprio(1);
#pragma unroll
      for (int nf = 0; nf < 4; ++nf) {
        acc[mbase][nf]     = MFMA16(a[0][0], b[nf][0], acc[mbase][nf]);
        acc[mbase][nf]     = MFMA16(a[0][1], b[nf][1], acc[mbase][nf]);
        acc[mbase + 1][nf] = MFMA16(a[1][0], b[nf][0], acc[mbase + 1][nf]);
        acc[mbase + 1][nf] = MFMA16(a[1][1], b[nf][1], acc[mbase + 1][nf]);
      }
      __builtin_amdgcn_s_setprio(0);
    };

    // quadrant pipeline: read next A-pair while MFMAing current (reg-only)
#pragma unroll
    for (int i = 0; i < 2; ++i) { a1[i][0] = LDA_(slot, 2 + i, 0); a1[i][1] = LDA_(slot, 2 + i, 1); }
    QUAD(0, a0);
#pragma unroll
    for (int i = 0; i < 2; ++i) { a0[i][0] = LDA_(slot, 4 + i, 0); a0[i][1] = LDA_(slot, 4 + i, 1); }
    QUAD(2, a1);
#pragma unroll
    for (int i = 0; i < 2; ++i) { a1[i][0] = LDA_(slot, 6 + i, 0); a1[i][1] = LDA_(slot, 6 + i, 1); }
    QUAD(4, a0);
    QUAD(6, a1);

    LGKM0();        // all reads of this slot complete
    BARRIER();      // ... in every wave
    SCHED0();
    if (kt + 2 < NT) {
      STAGE(slot, kt + 2);   // overwrite now-dead slot; stays in flight
      SCHED0();
      VMW8();                // tile kt+1 landed (kt+2's 8 still flying)
    } else if (kt + 1 < NT) {
      VMW0();                // tail: tile kt+1 landed
    }
    BARRIER();
    SCHED0();
  }

#pragma unroll
  for (int nf = 0; nf < 4; ++nf) {
    const int col = bn0 + wc0 + nf * 16 + fr;
    const float bv = bias[col];
#pragma unroll
    for (int m = 0; m < 8; ++m) {
      const int row0 = bm0 + wr0 + m * 16 + fq * 4;
#pragma unroll
      for (int r = 0; r < 4; ++r) {
        float v = fmaxf(acc[m][nf][r] + bv, 0.f);
        C[(size_t)(row0 + r) * ldc + col] = (f16)v;
      }
    }
  }
}

// ---------------------------------------------------------------------------
// Heads: mean = h12@Wm^T + bm ; log_std = clip(h22@Wls^T + bls, -20, 2). fp32 out.
// ---------------------------------------------------------------------------
__global__ __launch_bounds__(256) void head_kernel(
    const f16* __restrict__ H1, const f16* __restrict__ H2,
    const f16* __restrict__ Wm, const float* __restrict__ bm,
    const f16* __restrict__ Wls, const float* __restrict__ bls,
    float* __restrict__ OUT, int M, int K)
{
  const int tid = threadIdx.x, wid = tid >> 6, lane = tid & 63;
  const int m0 = blockIdx.x * 64 + wid * 16;
  const int kb = (lane >> 4) * 8, fr = lane & 15, fq = lane >> 4;

  f32x4 a1[2] = {}, a2[2] = {};
  for (int k0 = 0; k0 < K; k0 += 32) {
    f16x8 f1 = *(const f16x8*)&H1[(size_t)(m0 + fr) * K + k0 + kb];
    f16x8 f2 = *(const f16x8*)&H2[(size_t)(m0 + fr) * K + k0 + kb];
#pragma unroll
    for (int n = 0; n < 2; ++n) {
      f16x8 wm = *(const f16x8*)&Wm[(size_t)(n * 16 + fr) * K + k0 + kb];
      f16x8 wl = *(const f16x8*)&Wls[(size_t)(n * 16 + fr) * K + k0 + kb];
      a1[n] = MFMA16(f1, wm, a1[n]);
      a2[n] = MFMA16(f2, wl, a2[n]);
    }
  }

#pragma unroll
  for (int n = 0; n < 2; ++n) {
    const int col = n * 16 + fr;
    const float bvm = bm[col];
    const float bvl = bls[col];
#pragma unroll
    for (int r = 0; r < 4; ++r) {
      const int row = m0 + fq * 4 + r;
      OUT[(size_t)row * 32 + col] = a1[n][r] + bvm;
      float lv = a2[n][r] + bvl;
      OUT[(size_t)M * 32 + (size_t)row * 32 + col] = fminf(fmaxf(lv, -20.f), 2.f);
    }
  }
}

// ---------------------------------------------------------------------------
extern "C" void kernel_launch(void* const* d_in, const int* in_sizes, int n_in,
                              void* d_out, int out_size, void* d_ws, size_t ws_size,
                              hipStream_t stream) {
  const float* state = (const float*)d_in[0];
  const float* W_lif = (const float*)d_in[1];
  const float* b_lif = (const float*)d_in[2];
  const float* W11   = (const float*)d_in[3];
  const float* b11   = (const float*)d_in[4];
  const float* W12   = (const float*)d_in[5];
  const float* b12   = (const float*)d_in[6];
  const float* W21   = (const float*)d_in[7];
  const float* b21   = (const float*)d_in[8];
  const float* W22   = (const float*)d_in[9];
  const float* b22   = (const float*)d_in[10];
  const float* Wm    = (const float*)d_in[11];
  const float* bm    = (const float*)d_in[12];
  const float* Wls   = (const float*)d_in[13];
  const float* bls   = (const float*)d_in[14];
  float* out = (float*)d_out;

  const int B = 4096, IN = 512, H = 2048;
  char* ws = (char*)d_ws;
  // layout (bytes), peak 80.0 MB:
  f16* x    = (f16*)(ws);
  f16* h1   = (f16*)(ws + 16777216);
  f16* h2   = (f16*)(ws + 33554432);
  f16* s16  = (f16*)(ws + 50331648);
  f16* wl16 = (f16*)(ws + 71303168);
  f16* w11h = (f16*)(ws + 50331648);
  f16* w21h = (f16*)(ws + 58720256);
  f16* h22  = (f16*)(ws + 50331648);
  f16* w12h = (f16*)(ws + 67108864);
  f16* w22h = (f16*)(ws + 75497472);
  f16* wmh  = (f16*)(ws + 67108864);
  f16* wlsh = (f16*)(ws + 67239936);
  f16* h12  = x;

  // 1) converts for LIF
  cvt_kernel<<<(B * 5 * IN / 8) / 256, 256, 0, stream>>>(state, s16, B * 5 * IN / 8);
  cvt_kernel<<<(H * IN / 8) / 256, 256, 0, stream>>>(W_lif, wl16, H * IN / 8);

  // 2) fused fc-GEMM + LIF -> x
  lif_kernel<<<1024, 256, 0, stream>>>(s16, wl16, b_lif, x);

  // 3) layer-1: cvt W11+W21 (over s16), fused 256^2 GEMM -> h1, h2
  cvt2_kernel<<<2 * (H * H / 8) / 256, 256, 0, stream>>>(W11, W21, w11h, w21h, H * H / 8);
  trunk256_kernel<<<256, 512, 0, stream>>>(x, x, H, w11h, w21h, b11, b21,
                                           h1, h2, H, 16, 8, H);

  // 4) layer-2: cvt W12+W22, fused 256^2 GEMM -> h12 (over x), h22
  cvt2_kernel<<<2 * (H * H / 8) / 256, 256, 0, stream>>>(W12, W22, w12h, w22h, H * H / 8);
  trunk256_kernel<<<256, 512, 0, stream>>>(h1, h2, H, w12h, w22h, b12, b22,
                                           h12, h22, H, 16, 8, H);

  // 5) heads -> d_out = [mean | log_std] fp32
  cvt2_kernel<<<2 * (32 * H / 8) / 256, 256, 0, stream>>>(Wm, Wls, wmh, wlsh, 32 * H / 8);
  head_kernel<<<B / 64, 256, 0, stream>>>(h12, h22, wmh, bm, wlsh, bls, out, B, H);
}

// Round 6
// 285.006 us; speedup vs baseline: 1.2836x; 1.0378x over previous
//
#include <hip/hip_runtime.h>
#include <hip/hip_bf16.h>

// GaussianPolicy: SNN-LIF frontend + 2-branch MLP heads.
// B=4096, IN=512, H=2048, A=32. fp32 in/out; fp16 MFMA compute internally.
// Trunk GEMMs: 256x256 tile, BK=64, 8 waves, XOR-swizzled LDS (T2),
// counted vmcnt pipeline (T3/T4), setprio (T5).
// LIF: same schedule class, 128x128 tile, 5 s-slices sequential with
// per-thread (mem,cnt) LIF state carried across slices.

typedef _Float16 f16;
using f32x4 = __attribute__((ext_vector_type(4))) float;
using f16x8 = __attribute__((ext_vector_type(8))) f16;   // 8 fp16 = 4 VGPRs

#define MFMA16(a, b, c) __builtin_amdgcn_mfma_f32_16x16x32_f16((a), (b), (c), 0, 0, 0)
#define VMW8()  asm volatile("s_waitcnt vmcnt(8)" ::: "memory")
#define VMW4()  asm volatile("s_waitcnt vmcnt(4)" ::: "memory")
#define VMW0()  asm volatile("s_waitcnt vmcnt(0)" ::: "memory")
#define LGKM0() asm volatile("s_waitcnt lgkmcnt(0)" ::: "memory")
#define BARRIER() __builtin_amdgcn_s_barrier()
#define SCHED0() __builtin_amdgcn_sched_barrier(0)

__device__ __forceinline__ void gload16(const void* g, void* l) {
  // async global->LDS, 16B/lane; LDS dest must be wave-uniform base + lane*16
  __builtin_amdgcn_global_load_lds(
      (const __attribute__((address_space(1))) unsigned int*)g,
      (__attribute__((address_space(3))) unsigned int*)l, 16, 0, 0);
}

// ---------------------------------------------------------------------------
// fp32 -> fp16 convert, 8 elems/thread
// ---------------------------------------------------------------------------
__global__ __launch_bounds__(256) void cvt_kernel(
    const float* __restrict__ src, f16* __restrict__ dst, int n8)
{
  int i = blockIdx.x * 256 + threadIdx.x;
  if (i >= n8) return;
  const float4* s4 = (const float4*)src;
  float4 a = s4[(size_t)i * 2], b = s4[(size_t)i * 2 + 1];
  f16x8 d;
  d[0] = (f16)a.x; d[1] = (f16)a.y; d[2] = (f16)a.z; d[3] = (f16)a.w;
  d[4] = (f16)b.x; d[5] = (f16)b.y; d[6] = (f16)b.z; d[7] = (f16)b.w;
  *(f16x8*)(dst + (size_t)i * 8) = d;
}

// two equal-size tensors in one dispatch (saves a launch)
__global__ __launch_bounds__(256) void cvt2_kernel(
    const float* __restrict__ s0, const float* __restrict__ s1,
    f16* __restrict__ d0, f16* __restrict__ d1, int n8each)
{
  int i = blockIdx.x * 256 + threadIdx.x;
  const float* src = (i < n8each) ? s0 : s1;
  f16* dst = (i < n8each) ? d0 : d1;
  int k = (i < n8each) ? i : i - n8each;
  if (k >= n8each) return;
  const float4* s4 = (const float4*)src;
  float4 a = s4[(size_t)k * 2], b = s4[(size_t)k * 2 + 1];
  f16x8 d;
  d[0] = (f16)a.x; d[1] = (f16)a.y; d[2] = (f16)a.z; d[3] = (f16)a.w;
  d[4] = (f16)b.x; d[5] = (f16)b.y; d[6] = (f16)b.z; d[7] = (f16)b.w;
  *(f16x8*)(dst + (size_t)k * 8) = d;
}

// ---------------------------------------------------------------------------
// LIF kernel, trunk256-class schedule. Tile 128(M=batch) x 128(N=hidden),
// BK=64, 8 waves (2Mx4N), wave 64x32 = 4x2 frags. 5 s-slices sequential
// (global k-tile g in [0,40), slice s = g>>3); per-thread LIF state
// (mem,cnt) updated at each slice boundary; spike derived from mem.
// LDS A,B 2 slots each [128][64] f16 XOR-swizzled = 64KB.
// ---------------------------------------------------------------------------
__global__ __launch_bounds__(512, 1) void lif256_kernel(
    const f16* __restrict__ S,    // [4096*5, 512] fp16 (row (b*5+s))
    const f16* __restrict__ W,    // [2048, 512] fp16
    const float* __restrict__ bl, // [2048] fp32
    f16* __restrict__ X)          // [4096, 2048] fp16
{
  __shared__ alignas(16) f16 lds[4][128 * 64];   // [0,1]=A slots, [2,3]=B slots

  const int tid = threadIdx.x, wid = tid >> 6, lane = tid & 63;
  // XCD swizzle (nwg=512): consecutive wg -> same XCD; bn fastest so the 16
  // blocks sharing an S row-slice are L2-co-resident on one XCD.
  const int wg = ((int)blockIdx.x % 8) * 64 + (int)blockIdx.x / 8;
  const int bn = wg & 15, bm = wg >> 4;          // nbn=16, nbm=32
  const int b0 = bm * 128, h0 = bn * 128;
  const int wr0 = (wid >> 2) * 64, wc0 = (wid & 3) * 32;
  const int fr = lane & 15, fq = lane >> 4;
  const int sr = tid >> 3, scb = (tid & 7) * 16;  // staging row-in-64, col byte

  f32x4 acc[4][2] = {};
  float mem[4][2][4] = {};
  float cnt[4][2][4] = {};

  auto STAGE = [&](int slot, int g) {
    const int s = g >> 3, k0 = (g & 7) * 64;
#pragma unroll
    for (int l = 0; l < 2; ++l) {
      const int row = l * 64 + sr;
      const int c2 = scb ^ ((row & 7) << 4);      // pre-swizzled source col (bytes)
      gload16(S + ((size_t)(b0 + row) * 5 + s) * 512 + k0 + (c2 >> 1),
              &lds[slot][l * 4096 + tid * 8]);
    }
#pragma unroll
    for (int l = 0; l < 2; ++l) {
      const int row = l * 64 + sr;
      const int c2 = scb ^ ((row & 7) << 4);
      gload16(W + (size_t)(h0 + row) * 512 + k0 + (c2 >> 1),
              &lds[2 + slot][l * 4096 + tid * 8]);
    }
  };

  auto LDA_ = [&](int slot, int mf, int ks) -> f16x8 {
    const int row = wr0 + mf * 16 + fr;
    const int c = (ks * 64 + fq * 16) ^ ((row & 7) << 4);
    return *(const f16x8*)&lds[slot][row * 64 + (c >> 1)];
  };
  auto LDB_ = [&](int slot, int nf, int ks) -> f16x8 {
    const int row = wc0 + nf * 16 + fr;
    const int c = (ks * 64 + fq * 16) ^ ((row & 7) << 4);
    return *(const f16x8*)&lds[2 + slot][row * 64 + (c >> 1)];
  };

  const float bias[2] = { bl[h0 + wc0 + fr], bl[h0 + wc0 + 16 + fr] };

  STAGE(0, 0);
  STAGE(1, 1);
  VMW4();          // tile 0 landed; tile 1's 4 loads stay in flight
  BARRIER();
  SCHED0();

  for (int g = 0; g < 40; ++g) {
    const int slot = g & 1;

    f16x8 b[2][2], a[4][2];
#pragma unroll
    for (int nf = 0; nf < 2; ++nf) {
      b[nf][0] = LDB_(slot, nf, 0);
      b[nf][1] = LDB_(slot, nf, 1);
    }
#pragma unroll
    for (int mf = 0; mf < 4; ++mf) {
      a[mf][0] = LDA_(slot, mf, 0);
      a[mf][1] = LDA_(slot, mf, 1);
    }

    __builtin_amdgcn_s_setprio(1);
#pragma unroll
    for (int mf = 0; mf < 4; ++mf)
#pragma unroll
      for (int nf = 0; nf < 2; ++nf) {
        acc[mf][nf] = MFMA16(a[mf][0], b[nf][0], acc[mf][nf]);
        acc[mf][nf] = MFMA16(a[mf][1], b[nf][1], acc[mf][nf]);
      }
    __builtin_amdgcn_s_setprio(0);

    if ((g & 7) == 7) {
      // slice boundary: 3 LIF reps with fc = acc + bias; reset acc
#pragma unroll
      for (int mf = 0; mf < 4; ++mf)
#pragma unroll
        for (int nf = 0; nf < 2; ++nf) {
#pragma unroll
          for (int r = 0; r < 4; ++r) {
            const float fc = acc[mf][nf][r] + bias[nf];
            float m = mem[mf][nf][r], c = cnt[mf][nf][r];
#pragma unroll
            for (int j = 0; j < 3; ++j) {
              m = ((m > 0.2f) ? 0.f : m * 0.2f) + fc;   // DECAY=0.2, spike resets
              c += (m > 0.2f) ? 1.f : 0.f;              // THRESH=0.2
            }
            mem[mf][nf][r] = m; cnt[mf][nf][r] = c;
          }
          acc[mf][nf] = f32x4{0.f, 0.f, 0.f, 0.f};
        }
    }

    LGKM0();        // all reads of this slot complete
    BARRIER();      // ... in every wave
    SCHED0();
    if (g + 2 < 40) {
      STAGE(slot, g + 2);   // overwrite now-dead slot; stays in flight
      SCHED0();
      VMW4();               // tile g+1 landed (g+2's 4 still flying)
    } else if (g + 1 < 40) {
      VMW0();               // tail
    }
    BARRIER();
    SCHED0();
  }

#pragma unroll
  for (int nf = 0; nf < 2; ++nf) {
    const int col = h0 + wc0 + nf * 16 + fr;
#pragma unroll
    for (int mf = 0; mf < 4; ++mf) {
      const int row0 = b0 + wr0 + mf * 16 + fq * 4;
#pragma unroll
      for (int r = 0; r < 4; ++r)
        X[(size_t)(row0 + r) * 2048 + col] = (f16)(cnt[mf][nf][r] / 15.0f);
    }
  }
}

// ---------------------------------------------------------------------------
// Trunk GEMM: C = relu(A @ W^T + bias), fp16 in/out, fp32 bias/accum.
// 256x256 tile, BK=64, 8 waves (2Mx4N), wave output 128x64 = 8x4 frags.
// (unchanged — proven round 5)
// ---------------------------------------------------------------------------
__global__ __launch_bounds__(512, 2) void trunk256_kernel(
    const f16* __restrict__ A0, const f16* __restrict__ A1, int lda,
    const f16* __restrict__ W0, const f16* __restrict__ W1,
    const float* __restrict__ bb0, const float* __restrict__ bb1,
    f16* __restrict__ C0, f16* __restrict__ C1, int ldc,
    int nbm, int nbn_half, int K)
{
  __shared__ alignas(16) f16 lds[4][256 * 64];   // [0,1]=A slots, [2,3]=B slots

  const int tid = threadIdx.x, wid = tid >> 6, lane = tid & 63;
  const int nwg = nbm * nbn_half * 2, q8 = nwg / 8;
  const int wg = ((int)blockIdx.x % 8) * q8 + (int)blockIdx.x / 8;
  const int bmi = wg % nbm, t = wg / nbm;
  const int half = (t >= nbn_half);
  const f16* Ap = half ? A1 : A0;
  const f16* Wp = half ? W1 : W0;
  const float* bias = half ? bb1 : bb0;
  f16* C = half ? C1 : C0;
  const int bm0 = bmi * 256;
  const int bn0 = (half ? t - nbn_half : t) * 256;

  const int wr0 = (wid >> 2) * 128, wc0 = (wid & 3) * 64;
  const int fr = lane & 15, fq = lane >> 4;
  const int sr = tid >> 3, scb = (tid & 7) * 16;

  f32x4 acc[8][4] = {};
  const int NT = K / 64;

  auto STAGE = [&](int slot, int kt) {
    const int k0 = kt * 64;
#pragma unroll
    for (int l = 0; l < 4; ++l) {
      const int row = l * 64 + sr;
      const int c2 = scb ^ ((row & 7) << 4);
      gload16(Ap + (size_t)(bm0 + row) * lda + k0 + (c2 >> 1),
              &lds[slot][l * 4096 + tid * 8]);
    }
#pragma unroll
    for (int l = 0; l < 4; ++l) {
      const int row = l * 64 + sr;
      const int c2 = scb ^ ((row & 7) << 4);
      gload16(Wp + (size_t)(bn0 + row) * K + k0 + (c2 >> 1),
              &lds[2 + slot][l * 4096 + tid * 8]);
    }
  };

  auto LDA_ = [&](int slot, int mf, int ks) -> f16x8 {
    const int row = wr0 + mf * 16 + fr;
    const int c = (ks * 64 + fq * 16) ^ ((row & 7) << 4);
    return *(const f16x8*)&lds[slot][row * 64 + (c >> 1)];
  };
  auto LDB_ = [&](int slot, int nf, int ks) -> f16x8 {
    const int row = wc0 + nf * 16 + fr;
    const int c = (ks * 64 + fq * 16) ^ ((row & 7) << 4);
    return *(const f16x8*)&lds[2 + slot][row * 64 + (c >> 1)];
  };

  STAGE(0, 0);
  STAGE(1, 1);
  VMW8();          // tile 0 landed; tile 1's 8 loads stay in flight
  BARRIER();
  SCHED0();

  for (int kt = 0; kt < NT; ++kt) {
    const int slot = kt & 1;

    f16x8 b[4][2];
#pragma unroll
    for (int nf = 0; nf < 4; ++nf) {
      b[nf][0] = LDB_(slot, nf, 0);
      b[nf][1] = LDB_(slot, nf, 1);
    }
    f16x8 a0[2][2], a1[2][2];
#pragma unroll
    for (int i = 0; i < 2; ++i) {
      a0[i][0] = LDA_(slot, i, 0);
      a0[i][1] = LDA_(slot, i, 1);
    }

    auto QUAD = [&](int mbase, f16x8 (&a)[2][2]) {
      __builtin_amdgcn_s_setprio(1);
#pragma unroll
      for (int nf = 0; nf < 4; ++nf) {
        acc[mbase][nf]     = MFMA16(a[0][0], b[nf][0], acc[mbase][nf]);
        acc[mbase][nf]     = MFMA16(a[0][1], b[nf][1], acc[mbase][nf]);
        acc[mbase + 1][nf] = MFMA16(a[1][0], b[nf][0], acc[mbase + 1][nf]);
        acc[mbase + 1][nf] = MFMA16(a[1][1], b[nf][1], acc[mbase + 1][nf]);
      }
      __builtin_amdgcn_s_setprio(0);
    };

#pragma unroll
    for (int i = 0; i < 2; ++i) { a1[i][0] = LDA_(slot, 2 + i, 0); a1[i][1] = LDA_(slot, 2 + i, 1); }
    QUAD(0, a0);
#pragma unroll
    for (int i = 0; i < 2; ++i) { a0[i][0] = LDA_(slot, 4 + i, 0); a0[i][1] = LDA_(slot, 4 + i, 1); }
    QUAD(2, a1);
#pragma unroll
    for (int i = 0; i < 2; ++i) { a1[i][0] = LDA_(slot, 6 + i, 0); a1[i][1] = LDA_(slot, 6 + i, 1); }
    QUAD(4, a0);
    QUAD(6, a1);

    LGKM0();
    BARRIER();
    SCHED0();
    if (kt + 2 < NT) {
      STAGE(slot, kt + 2);
      SCHED0();
      VMW8();
    } else if (kt + 1 < NT) {
      VMW0();
    }
    BARRIER();
    SCHED0();
  }

#pragma unroll
  for (int nf = 0; nf < 4; ++nf) {
    const int col = bn0 + wc0 + nf * 16 + fr;
    const float bv = bias[col];
#pragma unroll
    for (int m = 0; m < 8; ++m) {
      const int row0 = bm0 + wr0 + m * 16 + fq * 4;
#pragma unroll
      for (int r = 0; r < 4; ++r) {
        float v = fmaxf(acc[m][nf][r] + bv, 0.f);
        C[(size_t)(row0 + r) * ldc + col] = (f16)v;
      }
    }
  }
}

// ---------------------------------------------------------------------------
// Heads: mean = h12@Wm^T + bm ; log_std = clip(h22@Wls^T + bls, -20, 2). fp32 out.
// ---------------------------------------------------------------------------
__global__ __launch_bounds__(256) void head_kernel(
    const f16* __restrict__ H1, const f16* __restrict__ H2,
    const f16* __restrict__ Wm, const float* __restrict__ bm,
    const f16* __restrict__ Wls, const float* __restrict__ bls,
    float* __restrict__ OUT, int M, int K)
{
  const int tid = threadIdx.x, wid = tid >> 6, lane = tid & 63;
  const int m0 = blockIdx.x * 64 + wid * 16;
  const int kb = (lane >> 4) * 8, fr = lane & 15, fq = lane >> 4;

  f32x4 a1[2] = {}, a2[2] = {};
  for (int k0 = 0; k0 < K; k0 += 32) {
    f16x8 f1 = *(const f16x8*)&H1[(size_t)(m0 + fr) * K + k0 + kb];
    f16x8 f2 = *(const f16x8*)&H2[(size_t)(m0 + fr) * K + k0 + kb];
#pragma unroll
    for (int n = 0; n < 2; ++n) {
      f16x8 wm = *(const f16x8*)&Wm[(size_t)(n * 16 + fr) * K + k0 + kb];
      f16x8 wl = *(const f16x8*)&Wls[(size_t)(n * 16 + fr) * K + k0 + kb];
      a1[n] = MFMA16(f1, wm, a1[n]);
      a2[n] = MFMA16(f2, wl, a2[n]);
    }
  }

#pragma unroll
  for (int n = 0; n < 2; ++n) {
    const int col = n * 16 + fr;
    const float bvm = bm[col];
    const float bvl = bls[col];
#pragma unroll
    for (int r = 0; r < 4; ++r) {
      const int row = m0 + fq * 4 + r;
      OUT[(size_t)row * 32 + col] = a1[n][r] + bvm;
      float lv = a2[n][r] + bvl;
      OUT[(size_t)M * 32 + (size_t)row * 32 + col] = fminf(fmaxf(lv, -20.f), 2.f);
    }
  }
}

// ---------------------------------------------------------------------------
extern "C" void kernel_launch(void* const* d_in, const int* in_sizes, int n_in,
                              void* d_out, int out_size, void* d_ws, size_t ws_size,
                              hipStream_t stream) {
  const float* state = (const float*)d_in[0];
  const float* W_lif = (const float*)d_in[1];
  const float* b_lif = (const float*)d_in[2];
  const float* W11   = (const float*)d_in[3];
  const float* b11   = (const float*)d_in[4];
  const float* W12   = (const float*)d_in[5];
  const float* b12   = (const float*)d_in[6];
  const float* W21   = (const float*)d_in[7];
  const float* b21   = (const float*)d_in[8];
  const float* W22   = (const float*)d_in[9];
  const float* b22   = (const float*)d_in[10];
  const float* Wm    = (const float*)d_in[11];
  const float* bm    = (const float*)d_in[12];
  const float* Wls   = (const float*)d_in[13];
  const float* bls   = (const float*)d_in[14];
  float* out = (float*)d_out;

  const int B = 4096, IN = 512, H = 2048;
  char* ws = (char*)d_ws;
  // layout (bytes), peak 80.0 MB:
  f16* x    = (f16*)(ws);
  f16* h1   = (f16*)(ws + 16777216);
  f16* h2   = (f16*)(ws + 33554432);
  f16* s16  = (f16*)(ws + 50331648);
  f16* wl16 = (f16*)(ws + 71303168);
  f16* w11h = (f16*)(ws + 50331648);
  f16* w21h = (f16*)(ws + 58720256);
  f16* h22  = (f16*)(ws + 50331648);
  f16* w12h = (f16*)(ws + 67108864);
  f16* w22h = (f16*)(ws + 75497472);
  f16* wmh  = (f16*)(ws + 67108864);
  f16* wlsh = (f16*)(ws + 67239936);
  f16* h12  = x;

  // 1) converts for LIF
  cvt_kernel<<<(B * 5 * IN / 8) / 256, 256, 0, stream>>>(state, s16, B * 5 * IN / 8);
  cvt_kernel<<<(H * IN / 8) / 256, 256, 0, stream>>>(W_lif, wl16, H * IN / 8);

  // 2) fused fc-GEMM + LIF -> x  (trunk256-class schedule)
  lif256_kernel<<<512, 512, 0, stream>>>(s16, wl16, b_lif, x);

  // 3) layer-1: cvt W11+W21 (over s16), fused 256^2 GEMM -> h1, h2
  cvt2_kernel<<<2 * (H * H / 8) / 256, 256, 0, stream>>>(W11, W21, w11h, w21h, H * H / 8);
  trunk256_kernel<<<256, 512, 0, stream>>>(x, x, H, w11h, w21h, b11, b21,
                                           h1, h2, H, 16, 8, H);

  // 4) layer-2: cvt W12+W22, fused 256^2 GEMM -> h12 (over x), h22
  cvt2_kernel<<<2 * (H * H / 8) / 256, 256, 0, stream>>>(W12, W22, w12h, w22h, H * H / 8);
  trunk256_kernel<<<256, 512, 0, stream>>>(h1, h2, H, w12h, w22h, b12, b22,
                                           h12, h22, H, 16, 8, H);

  // 5) heads -> d_out = [mean | log_std] fp32
  cvt2_kernel<<<2 * (32 * H / 8) / 256, 256, 0, stream>>>(Wm, Wls, wmh, wlsh, 32 * H / 8);
  head_kernel<<<B / 64, 256, 0, stream>>>(h12, h22, wmh, bm, wlsh, bls, out, B, H);
}